// Round 15
// baseline (402.955 us; speedup 1.0000x reference)
//
#include <hip/hip_runtime.h>
#include <hip/hip_bf16.h>

typedef unsigned int u32;
typedef unsigned short u16;

#define DEVINL __device__ __forceinline__

constexpr int Nn  = 25000;
constexpr int Ee  = 100000;
constexpr int NCc = 8000;
constexpr int Aa  = 50000;
constexpr int ECc = 24000;
constexpr int TCOLS = 1088;     // 34 k-rows * 32 o-cols
constexpr int WPSZ  = TCOLS*32; // one packed weight set
constexpr int TSP   = 1064;     // LDS T row stride (u16)
constexpr int NB_N = (Nn + 255)/256;   // 98
constexpr int NB_C = (NCc + 255)/256;  // 32
constexpr int NCH  = 2*(NB_N + NB_C);  // 260 scan chunks

typedef float f32x4 __attribute__((ext_vector_type(4)));
typedef short s16x8 __attribute__((ext_vector_type(8)));

DEVINL float b2f(u16 u){ union{u32 i;float f;}v; v.i = ((u32)u)<<16; return v.f; }
DEVINL float bfl(u32 u){ union{u32 i;float f;}v; v.i = u<<16; return v.f; }
DEVINL float bfh(u32 u){ union{u32 i;float f;}v; v.i = u & 0xffff0000u; return v.f; }
DEVINL u16 f2b(float f){ union{float f;u32 i;}v; v.f=f; u32 i=v.i;
  return (u16)((i + 0x7fffu + ((i>>16)&1u)) >> 16); }
DEVINL u32 pk2(float a, float b){ return (u32)f2b(a) | ((u32)f2b(b) << 16); }
DEVINL float ldw(const void* p, long i, int f){
  return f ? ((const float*)p)[i] : b2f(((const u16*)p)[i]);
}

// ---------- pre1: dtype detect (blocks 0..255) || all histograms (blocks 256+) ----------
__global__ __launch_bounds__(256) void k_pre1(const u16* __restrict__ xp,
                      u32* __restrict__ maxbits, int* __restrict__ zcnt,
                      int* __restrict__ done, int* __restrict__ flag,
                      const int* __restrict__ ei, const int* __restrict__ cei,
                      const int* __restrict__ n2c,
                      int* __restrict__ deg_nd, int* __restrict__ deg_ce,
                      int* __restrict__ deg_n2c, int* __restrict__ deg_c2n,
                      int* __restrict__ cnt_sn, int* __restrict__ cnt_sc){
  int bid = blockIdx.x;
  if (bid < 256){
    int n = Nn*32;
    float lm = 0.f; int lz = 0;
    for (int i = bid*256 + threadIdx.x; i < n; i += 256*256){
      u16 v = xp[i];
      if (v == 0) lz++;
      lm = fmaxf(lm, fabsf(b2f(v)));
    }
    #pragma unroll
    for (int off = 32; off; off >>= 1){
      lm = fmaxf(lm, __shfl_down(lm, off));
      lz += __shfl_down(lz, off);
    }
    if ((threadIdx.x & 63) == 0){
      atomicMax(maxbits, __float_as_uint(lm));
      atomicAdd(zcnt, lz);
    }
    __syncthreads();
    if (threadIdx.x == 0){
      __threadfence();
      if (atomicAdd(done, 1) == 255){
        float m = __uint_as_float(*maxbits);
        *flag = (m > 1e6f || *zcnt > n/4) ? 1 : 0;   // 1 => f32 inputs
      }
    }
  } else {
    int i = (bid - 256)*256 + threadIdx.x;
    if (i < Ee)                             atomicAdd(&deg_nd[ei[Ee + i]], 1);
    else if ((i -= Ee) < ECc)               atomicAdd(&deg_ce[cei[ECc + i]], 1);
    else if ((i -= ECc) < Aa)               atomicAdd(&deg_n2c[n2c[Aa + i]], 1);
    else if ((i -= Aa) < Aa)                atomicAdd(&deg_c2n[n2c[i]], 1);
    else if ((i -= Aa) < Ee)                atomicAdd(&cnt_sn[ei[i]], 1);
    else if ((i -= Ee) < ECc)               atomicAdd(&cnt_sc[cei[i]], 1);
  }
}

// ---------- fused scan (blocks 0..NCH-1, single-kernel via publish+spin) || wpack (blocks NCH+) ----------
__global__ __launch_bounds__(256) void k_scan_wpack(
    const int* __restrict__ c0, const int* __restrict__ c1,
    const int* __restrict__ c2, const int* __restrict__ c3,
    int* __restrict__ o0, int* __restrict__ o1, int* __restrict__ o2, int* __restrict__ o3,
    int* __restrict__ b0, int* __restrict__ b1, int* __restrict__ b2, int* __restrict__ b3,
    int* __restrict__ sdone,
    const void* __restrict__ nn2w, const void* __restrict__ nn2b, const void* __restrict__ rootw,
    const void* __restrict__ cnn2w, const void* __restrict__ cnn2b, const void* __restrict__ crootw,
    const int* __restrict__ flag, u16* __restrict__ Wp4){
  int bid = blockIdx.x;
  int tid = threadIdx.x;
  if (bid >= NCH){
    int i = (bid - NCH)*256 + tid;
    if (i >= 4*WPSZ) return;
    int set = i / WPSZ, j = i - set*WPSZ;
    int l = set >> 1, isC = set & 1;
    const void* W2 = isC ? cnn2w : nn2w;
    const void* B2 = isC ? cnn2b : nn2b;
    const void* RW = isC ? crootw : rootw;
    int f = *flag;
    int col = j >> 5, ii = j & 31;
    float v;
    if (col < 1024)      v = ldw(W2, (long)l*32768 + ((col>>5)<<10) + (ii<<5) + (col&31), f);
    else if (col < 1056) v = ldw(B2, (long)l*1024 + (ii<<5) + (col-1024), f);
    else                 v = ldw(RW, (long)l*1024 + (ii<<5) + (col-1056), f);
    Wp4[i] = f2b(v);
    return;
  }
  __shared__ int s[256];
  int seg, rb;
  if (bid < NB_N){ seg=0; rb=bid; }
  else if (bid < NB_N+NB_C){ seg=1; rb=bid-NB_N; }
  else if (bid < 2*NB_N+NB_C){ seg=2; rb=bid-NB_N-NB_C; }
  else { seg=3; rb=bid-2*NB_N-NB_C; }
  const int* cnt = seg==0?c0 : seg==1?c1 : seg==2?c2 : c3;
  int* offs = seg==0?o0 : seg==1?o1 : seg==2?o2 : o3;
  int* bs   = seg==0?b0 : seg==1?b1 : seg==2?b2 : b3;
  int M = (seg & 1) ? NCc : Nn;
  int i = rb*256 + tid;
  int v = (i < M) ? cnt[i] : 0;
  s[tid] = v; __syncthreads();
  for (int d = 1; d < 256; d <<= 1){
    int t = (tid >= d) ? s[tid-d] : 0;
    __syncthreads();
    s[tid] += t;
    __syncthreads();
  }
  int ex = s[tid] - v;          // exclusive within chunk
  if (tid == 255){
    atomicExch(&bs[rb], s[255]);
    __threadfence();
    atomicAdd(sdone, 1);
  }
  if (tid == 0){
    while (atomicAdd(sdone, 0) < NCH) __builtin_amdgcn_s_sleep(8);
  }
  __syncthreads();
  // spine prefix for this chunk = sum of earlier chunks' bsums (device-scope atomic reads)
  int contrib = (tid < rb) ? atomicAdd(&bs[tid], 0) : 0;
  s[tid] = contrib; __syncthreads();
  for (int d = 128; d; d >>= 1){
    if (tid < d) s[tid] += s[tid + d];
    __syncthreads();
  }
  if (i < M) offs[i] = ex + s[0];
}

// ---------- place: edge perms + assignment CSRs ----------
__global__ __launch_bounds__(256) void k_place(const int* __restrict__ ei, const int* __restrict__ cei,
                      const int* __restrict__ n2c,
                      const int* __restrict__ offs_n, const int* __restrict__ offs_c,
                      const int* __restrict__ offs_an, const int* __restrict__ offs_ac,
                      int* __restrict__ cur_n, int* __restrict__ cur_c,
                      int* __restrict__ cur_an, int* __restrict__ cur_ac,
                      int* __restrict__ perm_n, int* __restrict__ perm_c,
                      int* __restrict__ an2c, int* __restrict__ ac2n){
  int i = blockIdx.x*256 + threadIdx.x;
  if (i < Ee){
    int s = ei[i];
    perm_n[offs_n[s] + atomicAdd(&cur_n[s], 1)] = i;
  } else if ((i -= Ee) < ECc){
    int s = cei[i];
    perm_c[offs_c[s] + atomicAdd(&cur_c[s], 1)] = i;
  } else if ((i -= ECc) < Aa){
    int c = n2c[Aa + i];
    an2c[offs_ac[c] + atomicAdd(&cur_ac[c], 1)] = n2c[i];
  } else if ((i -= Aa) < Aa){
    int nd = n2c[i];
    ac2n[offs_an[nd] + atomicAdd(&cur_an[nd], 1)] = n2c[Aa + i];
  }
}

// ---------- gather edge payloads into sorted order ----------
__global__ __launch_bounds__(256) void k_gather(const int* __restrict__ ei, const int* __restrict__ cei,
                       const int* __restrict__ perm_n, const int* __restrict__ perm_c,
                       const void* __restrict__ ef, const void* __restrict__ cef,
                       const int* __restrict__ flag,
                       int2* __restrict__ sdp_n, float* __restrict__ efp_n,
                       int2* __restrict__ sdp_c, float* __restrict__ efp_c){
  int i = blockIdx.x*256 + threadIdx.x;
  int f = *flag;
  if (i < Ee*8){
    int p = i >> 3, j = i & 7;
    int e = perm_n[p];
    efp_n[i] = ldw(ef, (long)e*8 + j, f);
    if (j == 0) sdp_n[p] = make_int2(ei[e], ei[Ee + e]);
  } else if ((i -= Ee*8) < ECc*8){
    int p = i >> 3, j = i & 7;
    int e = perm_c[p];
    efp_c[i] = ldw(cef, (long)e*8 + j, f);
    if (j == 0) sdp_c[p] = make_int2(cei[e], cei[ECc + e]);
  }
}

// ---------- fused conv: work-stealing windows + afrag prefetch + streaming edges ----------
__global__ __launch_bounds__(512) void k_conv_fused(const void* __restrict__ base, int braw,
                           const float* __restrict__ addagg, const int* __restrict__ adddeg, int M,
                           const int2* __restrict__ sdp, const float* __restrict__ efp,
                           const int* __restrict__ offs, int E_,
                           const void* __restrict__ w1, long w1off,
                           const void* __restrict__ b1, long b1off,
                           const u16* __restrict__ Wp,
                           const void* __restrict__ rb, long rboff,
                           const int* __restrict__ flag,
                           int* __restrict__ wctr,
                           float* __restrict__ feat_root, float* __restrict__ agg){
  __shared__ __align__(16) u16 Ts[16*TSP];
  __shared__ float w1s[256];
  __shared__ __align__(8) u32 hws[8][4][16];
  __shared__ int wshare;
  int tid = threadIdx.x;
  int w = tid >> 6, lane = tid & 63;
  int quad = lane >> 4, lm = lane & 15;
  int f = *flag;
  if (tid < 256) w1s[tid] = ldw(w1, w1off + tid, f);
  float bb0 = ldw(b1, b1off + 2*lm, f);
  float bb1 = ldw(b1, b1off + 2*lm + 1, f);
  int nwin = (M + 15)/16;
  for (;;){
    if (tid == 0) wshare = atomicAdd(wctr, 1);
    __syncthreads();   // distribute window; also protects Ts reuse
    int win = wshare;
    if (win >= nwin) break;
    int n0 = win * 16;
    int n = n0 + lm;
    int nc = n < M ? n : M-1;
    long bidx = (long)nc*32 + quad*8;
    float fv[8];
    if (braw && f == 0){
      uint4 q = *(const uint4*)((const u16*)base + bidx);
      fv[0]=bfl(q.x); fv[1]=bfh(q.x); fv[2]=bfl(q.y); fv[3]=bfh(q.y);
      fv[4]=bfl(q.z); fv[5]=bfh(q.z); fv[6]=bfl(q.w); fv[7]=bfh(q.w);
    } else {
      const float4* bp = (const float4*)((const float*)base + bidx);
      float4 q0 = bp[0], q1 = bp[1];
      fv[0]=q0.x; fv[1]=q0.y; fv[2]=q0.z; fv[3]=q0.w;
      fv[4]=q1.x; fv[5]=q1.y; fv[6]=q1.z; fv[7]=q1.w;
    }
    if (addagg){
      int dg = adddeg[nc];
      float inv = 1.f/(float)(dg > 1 ? dg : 1);
      const float4* ap = (const float4*)(addagg + (size_t)nc*32 + quad*8);
      float4 a0 = ap[0], a1 = ap[1];
      fv[0]+=a0.x*inv; fv[1]+=a0.y*inv; fv[2]+=a0.z*inv; fv[3]+=a0.w*inv;
      fv[4]+=a1.x*inv; fv[5]+=a1.y*inv; fv[6]+=a1.z*inv; fv[7]+=a1.w*inv;
    }
    s16x8 bfrag;
    #pragma unroll
    for (int j = 0; j < 8; j++) bfrag[j] = (short)f2b(fv[j]);
    // phase 1: wave w -> col-tiles [9w, 9w+9) of 68, depth-1 afrag prefetch
    int ctbase = w*9;
    s16x8 afc = *(const s16x8*)(Wp + (size_t)(ctbase*16 + lm)*32 + quad*8);
    #pragma unroll 1
    for (int ti = 0; ti < 9; ti++){
      int ct = ctbase + ti;
      if (ct >= 68) break;
      s16x8 afn;
      bool have_n = (ti + 1 < 9) && (ct + 1 < 68);
      if (have_n) afn = *(const s16x8*)(Wp + (size_t)((ct+1)*16 + lm)*32 + quad*8);
      f32x4 acc = {0.f, 0.f, 0.f, 0.f};
      acc = __builtin_amdgcn_mfma_f32_16x16x32_bf16(afc, bfrag, acc, 0, 0, 0);
      int cb = ct*16 + quad*4;
      if (ct < 66){
        u32 lo = (u32)f2b(acc[0]) | ((u32)f2b(acc[1]) << 16);
        u32 hi = (u32)f2b(acc[2]) | ((u32)f2b(acc[3]) << 16);
        *(uint2*)&Ts[lm*TSP + cb] = make_uint2(lo, hi);
      } else if (n < M){
        int o = cb - 1056;
        float4 v = make_float4(acc[0] + ldw(rb, rboff+o,   f),
                               acc[1] + ldw(rb, rboff+o+1, f),
                               acc[2] + ldw(rb, rboff+o+2, f),
                               acc[3] + ldw(rb, rboff+o+3, f));
        *(float4*)&feat_root[(size_t)n*32 + o] = v;
      }
      if (have_n) afc = afn;
    }
    __syncthreads();
    // phase 2: streaming edges, 4/wave-iter, depth-2 prefetch
    int lo = offs[n0];
    int hi = (n0 + 16 < M) ? offs[n0 + 16] : E_;
    int eg = quad, kk = lm;
    int pos = lo + w*4;
    float ef0 = 0.f, ef1 = 0.f; int sd0 = 0, sd1 = 0;
    if (lane < 32){
      int idx = pos*8 + lane;        if (idx < hi*8) ef0 = efp[idx];
      idx = (pos+32)*8 + lane;       if (idx < hi*8) ef1 = efp[idx];
    } else if (lane < 40){
      int idx = pos*2 + (lane-32);   if (idx < hi*2) sd0 = ((const int*)sdp)[idx];
      idx = (pos+32)*2 + (lane-32);  if (idx < hi*2) sd1 = ((const int*)sdp)[idx];
    }
    for (; pos < hi; pos += 32){
      int np = pos + 64;
      float ef2 = 0.f; int sd2 = 0;
      if (lane < 32){ int idx = np*8 + lane; if (idx < hi*8) ef2 = efp[idx]; }
      else if (lane < 40){ int idx = np*2 + (lane-32); if (idx < hi*2) sd2 = ((const int*)sdp)[idx]; }
      int sn = __shfl(sd0, 32 + 2*eg);
      int dn = __shfl(sd0, 33 + 2*eg);
      bool valid = (pos + eg < hi);
      int sr = sn - n0; sr = sr < 0 ? 0 : (sr > 15 ? 15 : sr);
      float a0 = bb0, a1 = bb1;
      #pragma unroll
      for (int j = 0; j < 8; j++){
        float ev = __shfl(ef0, eg*8 + j);
        a0 += ev * w1s[j*32 + 2*kk];
        a1 += ev * w1s[j*32 + 2*kk+1];
      }
      hws[w][eg][kk] = pk2(fmaxf(a0, 0.f), fmaxf(a1, 0.f));
      if (valid){
        const u16* Tr = &Ts[sr*TSP];
        u32 vb = *(const u32*)&Tr[1024 + 2*kk];   // b2 row (h=1)
        float m0 = bfl(vb), m1 = bfh(vb);
        #pragma unroll
        for (int kq = 0; kq < 16; kq++){
          u32 hp = hws[w][eg][kq];
          float h0 = bfl(hp), h1 = bfh(hp);
          u32 v0 = *(const u32*)&Tr[(2*kq)*32 + 2*kk];
          u32 v1 = *(const u32*)&Tr[(2*kq+1)*32 + 2*kk];
          m0 += h0*bfl(v0) + h1*bfl(v1);
          m1 += h0*bfh(v0) + h1*bfh(v1);
        }
        float* ap = agg + (size_t)dn*32 + 2*kk;
        atomicAdd(ap,   m0);
        atomicAdd(ap+1, m1);
      }
      ef0 = ef1; sd0 = sd1; ef1 = ef2; sd1 = sd2;
    }
    __syncthreads();   // all waves done reading Ts before next window's phase 1
  }
}

// ---------- fused: feat = relu(agg/deg + froot); m = feat@w+b; scatter m into sagg ----------
__global__ __launch_bounds__(256) void k_update_lin(const float* __restrict__ agg, const int* __restrict__ deg,
                           const float* __restrict__ feat_root, int M,
                           const void* __restrict__ w, long woff,
                           const void* __restrict__ b, long boff,
                           const int* __restrict__ flag,
                           float* __restrict__ feat,
                           const int* __restrict__ sidx, const int* __restrict__ soffs,
                           const int* __restrict__ sdeg, float* __restrict__ sagg){
  __shared__ float wsm[1024], bs[32], rows[8][33];
  int tid = threadIdx.x;
  int f = *flag;
  for (int idx = tid; idx < 1024; idx += 256) wsm[idx] = ldw(w, woff + idx, f);
  if (tid < 32) bs[tid] = ldw(b, boff + tid, f);
  int nl = tid >> 5, o = tid & 31;
  int n = blockIdx.x*8 + nl;
  long i = (long)n*32 + o;
  if (n < M){
    int dg = deg[n];
    float d = (float)(dg > 1 ? dg : 1);
    float v = fmaxf(agg[i]/d + feat_root[i], 0.f);
    rows[nl][o] = v;
    feat[i] = v;
  }
  __syncthreads();
  if (n >= M) return;
  float acc = bs[o];
  #pragma unroll
  for (int j = 0; j < 32; j++) acc += rows[nl][j]*wsm[j*32+o];
  int slo = soffs[n], scnt = sdeg[n];
  for (int a = 0; a < scnt; a++)
    atomicAdd(&sagg[(size_t)sidx[slo + a]*32 + o], acc);
}

// ---------- final store ----------
__global__ __launch_bounds__(256) void k_store(const float* __restrict__ x, const float* __restrict__ xagg,
                      const int* __restrict__ xdeg, const float* __restrict__ c,
                      void* __restrict__ out, const int* __restrict__ flag){
  int i = blockIdx.x*256 + threadIdx.x;
  int tot = Nn*32 + NCc*32;
  if (i >= tot) return;
  float v;
  if (i < Nn*32){
    int n = i >> 5;
    int dg = xdeg[n];
    float d = (float)(dg > 1 ? dg : 1);
    v = x[i] + xagg[i]/d;
  } else v = c[i - Nn*32];
  if (*flag) ((float*)out)[i] = v;
  else       ((u16*)out)[i]   = f2b(v);
}

extern "C" void kernel_launch(void* const* d_in, const int* in_sizes, int n_in,
                              void* d_out, int out_size, void* d_ws, size_t ws_size,
                              hipStream_t stream){
  const int* ei  = (const int*)d_in[1];
  const int* n2c = (const int*)d_in[4];
  const int* cei = (const int*)d_in[5];
  const void *efr = d_in[2], *cefr = d_in[6];
  const void *nn1w = d_in[7], *nn1b = d_in[8], *nn2w = d_in[9], *nn2b = d_in[10],
             *rootw = d_in[11], *rootb = d_in[12], *n2cw = d_in[13], *n2cb = d_in[14],
             *cnn1w = d_in[15], *cnn1b = d_in[16], *cnn2w = d_in[17], *cnn2b = d_in[18],
             *crootw = d_in[19], *crootb = d_in[20], *c2nw = d_in[21], *c2nb = d_in[22];

  char* ws = (char*)d_ws;
  size_t off = 0;
  auto alloc = [&](size_t bytes){ void* p = ws + off; off += (bytes + 255) & ~(size_t)255; return p; };

  // ---- zeroed region (single memset) ----
  size_t zstart = off;
  float* aggE0  = (float*)alloc((size_t)Nn*32*4);
  float* aggE1  = (float*)alloc((size_t)Nn*32*4);
  float* caggE0 = (float*)alloc((size_t)NCc*32*4);
  float* caggE1 = (float*)alloc((size_t)NCc*32*4);
  float* caggS0 = (float*)alloc((size_t)NCc*32*4);
  float* caggS1 = (float*)alloc((size_t)NCc*32*4);
  float* aggS0  = (float*)alloc((size_t)Nn*32*4);
  float* aggS1  = (float*)alloc((size_t)Nn*32*4);
  int* deg_nd  = (int*)alloc((size_t)Nn*4);
  int* deg_ce  = (int*)alloc((size_t)NCc*4);
  int* deg_n2c = (int*)alloc((size_t)NCc*4);
  int* deg_c2n = (int*)alloc((size_t)Nn*4);
  int* cnt_sn  = (int*)alloc((size_t)Nn*4);
  int* cnt_sc  = (int*)alloc((size_t)NCc*4);
  int* cur_n   = (int*)alloc((size_t)Nn*4);
  int* cur_c   = (int*)alloc((size_t)NCc*4);
  int* cur_an  = (int*)alloc((size_t)Nn*4);
  int* cur_ac  = (int*)alloc((size_t)NCc*4);
  u32* maxbits = (u32*)alloc(256);
  int* zcnt  = (int*)((char*)maxbits + 4);
  int* flag  = (int*)((char*)maxbits + 8);
  int* done  = (int*)((char*)maxbits + 12);
  int* sdone = (int*)((char*)maxbits + 16);
  int* wctr0 = (int*)((char*)maxbits + 20);
  int* wctr1 = (int*)((char*)maxbits + 24);
  int* wctr2 = (int*)((char*)maxbits + 28);
  int* wctr3 = (int*)((char*)maxbits + 32);
  size_t zbytes = off - zstart;

  // ---- non-zeroed ----
  float* xB  = (float*)alloc((size_t)Nn*32*4);
  float* xC  = (float*)alloc((size_t)Nn*32*4);
  float* cC0 = (float*)alloc((size_t)NCc*32*4);
  float* cC1 = (float*)alloc((size_t)NCc*32*4);
  float* frn = (float*)alloc((size_t)Nn*32*4);
  float* frc = (float*)alloc((size_t)NCc*32*4);
  int* offs_n  = (int*)alloc((size_t)Nn*4);
  int* offs_c  = (int*)alloc((size_t)NCc*4);
  int* offs_an = (int*)alloc((size_t)Nn*4);
  int* offs_ac = (int*)alloc((size_t)NCc*4);
  int* bs0 = (int*)alloc(512); int* bs1 = (int*)alloc(512);
  int* bs2 = (int*)alloc(512); int* bs3 = (int*)alloc(512);
  int* perm_n = (int*)alloc((size_t)Ee*4);
  int* perm_c = (int*)alloc((size_t)ECc*4);
  int* an2c = (int*)alloc((size_t)Aa*4);
  int* ac2n = (int*)alloc((size_t)Aa*4);
  int2* sdp_n = (int2*)alloc((size_t)Ee*8);
  int2* sdp_c = (int2*)alloc((size_t)ECc*8);
  float* efp_n = (float*)alloc((size_t)Ee*8*4);
  float* efp_c = (float*)alloc((size_t)ECc*8*4);
  u16* Wp4 = (u16*)alloc((size_t)4*WPSZ*2);

  auto nb = [](int n){ return (n + 255)/256; };

  // 1. memset accumulators/counters
  hipMemsetAsync(ws + zstart, 0, zbytes, stream);
  // 2. detect || histograms
  k_pre1<<<256 + nb(2*Ee + 2*ECc + 2*Aa),256,0,stream>>>((const u16*)d_in[0],
      maxbits, zcnt, done, flag, ei, cei, n2c,
      deg_nd, deg_ce, deg_n2c, deg_c2n, cnt_sn, cnt_sc);
  // 3. fused scan || weight pack
  k_scan_wpack<<<NCH + nb(4*WPSZ),256,0,stream>>>(cnt_sn, cnt_sc, deg_c2n, deg_n2c,
      offs_n, offs_c, offs_an, offs_ac, bs0, bs1, bs2, bs3, sdone,
      nn2w, nn2b, rootw, cnn2w, cnn2b, crootw, flag, Wp4);
  // 4. place + gather
  k_place<<<nb(Ee+ECc+2*Aa),256,0,stream>>>(ei, cei, n2c, offs_n, offs_c, offs_an, offs_ac,
      cur_n, cur_c, cur_an, cur_ac, perm_n, perm_c, an2c, ac2n);
  k_gather<<<nb(8*(Ee+ECc)),256,0,stream>>>(ei, cei, perm_n, perm_c, efr, cefr, flag,
      sdp_n, efp_n, sdp_c, efp_c);

  // ---- layer 0 ----
  k_conv_fused<<<1024,512,0,stream>>>(d_in[0], 1, nullptr, nullptr, Nn, sdp_n, efp_n, offs_n, Ee,
      nn1w, 0, nn1b, 0, Wp4 + 0*WPSZ, rootb, 0, flag, wctr0, frn, aggE0);
  k_update_lin<<<(Nn+7)/8,256,0,stream>>>(aggE0, deg_nd, frn, Nn, n2cw, 0, n2cb, 0, flag,
      xB, ac2n, offs_an, deg_c2n, caggS0);
  k_conv_fused<<<1024,512,0,stream>>>(d_in[3], 1, caggS0, deg_n2c, NCc, sdp_c, efp_c, offs_c, ECc,
      cnn1w, 0, cnn1b, 0, Wp4 + 1*WPSZ, crootb, 0, flag, wctr1, frc, caggE0);
  k_update_lin<<<(NCc+7)/8,256,0,stream>>>(caggE0, deg_ce, frc, NCc, c2nw, 0, c2nb, 0, flag,
      cC0, an2c, offs_ac, deg_n2c, aggS0);
  // ---- layer 1 ----
  k_conv_fused<<<1024,512,0,stream>>>(xB, 0, aggS0, deg_c2n, Nn, sdp_n, efp_n, offs_n, Ee,
      nn1w, 256, nn1b, 32, Wp4 + 2*WPSZ, rootb, 32, flag, wctr2, frn, aggE1);
  k_update_lin<<<(Nn+7)/8,256,0,stream>>>(aggE1, deg_nd, frn, Nn, n2cw, 1024, n2cb, 32, flag,
      xC, ac2n, offs_an, deg_c2n, caggS1);
  k_conv_fused<<<1024,512,0,stream>>>(cC0, 0, caggS1, deg_n2c, NCc, sdp_c, efp_c, offs_c, ECc,
      cnn1w, 256, cnn1b, 32, Wp4 + 3*WPSZ, crootb, 32, flag, wctr3, frc, caggE1);
  k_update_lin<<<(NCc+7)/8,256,0,stream>>>(caggE1, deg_ce, frc, NCc, c2nw, 1024, c2nb, 32, flag,
      cC1, an2c, offs_ac, deg_n2c, aggS1);
  // ---- output ----
  k_store<<<nb(Nn*32 + NCc*32),256,0,stream>>>(xC, aggS1, deg_c2n, cC1, d_out, flag);
}

// Round 16
// 346.232 us; speedup vs baseline: 1.1638x; 1.1638x over previous
//
#include <hip/hip_runtime.h>
#include <hip/hip_bf16.h>

typedef unsigned int u32;
typedef unsigned short u16;

#define DEVINL __device__ __forceinline__

constexpr int Nn  = 25000;
constexpr int Ee  = 100000;
constexpr int NCc = 8000;
constexpr int Aa  = 50000;
constexpr int ECc = 24000;
constexpr int TCOLS = 1088;     // 34 k-rows * 32 o-cols
constexpr int WPSZ  = TCOLS*32; // one packed weight set
constexpr int TSP   = 1064;     // LDS T row stride (u16)
constexpr int NB_N = (Nn + 255)/256;   // 98
constexpr int NB_C = (NCc + 255)/256;  // 32

typedef float f32x4 __attribute__((ext_vector_type(4)));
typedef short s16x8 __attribute__((ext_vector_type(8)));

DEVINL float b2f(u16 u){ union{u32 i;float f;}v; v.i = ((u32)u)<<16; return v.f; }
DEVINL float bfl(u32 u){ union{u32 i;float f;}v; v.i = u<<16; return v.f; }
DEVINL float bfh(u32 u){ union{u32 i;float f;}v; v.i = u & 0xffff0000u; return v.f; }
DEVINL u16 f2b(float f){ union{float f;u32 i;}v; v.f=f; u32 i=v.i;
  return (u16)((i + 0x7fffu + ((i>>16)&1u)) >> 16); }
DEVINL u32 pk2(float a, float b){ return (u32)f2b(a) | ((u32)f2b(b) << 16); }
DEVINL float ldw(const void* p, long i, int f){
  return f ? ((const float*)p)[i] : b2f(((const u16*)p)[i]);
}

// ---------- dtype detection + flag (fused via last-block-done) ----------
__global__ __launch_bounds__(256) void k_detect(const u16* __restrict__ p, int n,
                        u32* __restrict__ maxbits, int* __restrict__ zcnt,
                        int* __restrict__ done, int* __restrict__ flag){
  int i0 = blockIdx.x*256 + threadIdx.x;
  float lm = 0.f; int lz = 0;
  for (int i = i0; i < n; i += gridDim.x*256){
    u16 v = p[i];
    if (v == 0) lz++;
    lm = fmaxf(lm, fabsf(b2f(v)));
  }
  #pragma unroll
  for (int off = 32; off; off >>= 1){
    lm = fmaxf(lm, __shfl_down(lm, off));
    lz += __shfl_down(lz, off);
  }
  if ((threadIdx.x & 63) == 0){
    atomicMax(maxbits, __float_as_uint(lm));
    atomicAdd(zcnt, lz);
  }
  __syncthreads();
  if (threadIdx.x == 0){
    __threadfence();
    if (atomicAdd(done, 1) == gridDim.x - 1){
      float m = __uint_as_float(*maxbits);
      *flag = (m > 1e6f || *zcnt > n/4) ? 1 : 0;   // 1 => f32 inputs
    }
  }
}

// ---------- all degree/count histograms ----------
__global__ __launch_bounds__(256) void k_count_all(const int* __restrict__ ei, const int* __restrict__ cei,
                          const int* __restrict__ n2c,
                          int* __restrict__ deg_nd, int* __restrict__ deg_ce,
                          int* __restrict__ deg_n2c, int* __restrict__ deg_c2n,
                          int* __restrict__ cnt_sn, int* __restrict__ cnt_sc){
  int i = blockIdx.x*256 + threadIdx.x;
  if (i < Ee)                             atomicAdd(&deg_nd[ei[Ee + i]], 1);
  else if ((i -= Ee) < ECc)               atomicAdd(&deg_ce[cei[ECc + i]], 1);
  else if ((i -= ECc) < Aa)               atomicAdd(&deg_n2c[n2c[Aa + i]], 1);
  else if ((i -= Aa) < Aa)                atomicAdd(&deg_c2n[n2c[i]], 1);
  else if ((i -= Aa) < Ee)                atomicAdd(&cnt_sn[ei[i]], 1);
  else if ((i -= Ee) < ECc)               atomicAdd(&cnt_sc[cei[i]], 1);
}

// ---------- hierarchical scan over 4 arrays ----------
__global__ __launch_bounds__(256) void k_scan_block(
    const int* __restrict__ c0, const int* __restrict__ c1,
    const int* __restrict__ c2, const int* __restrict__ c3,
    int* __restrict__ o0, int* __restrict__ o1, int* __restrict__ o2, int* __restrict__ o3,
    int* __restrict__ b0, int* __restrict__ b1, int* __restrict__ b2, int* __restrict__ b3){
  __shared__ int s[256];
  int bid = blockIdx.x, seg, rb;
  if (bid < NB_N){ seg=0; rb=bid; }
  else if (bid < NB_N+NB_C){ seg=1; rb=bid-NB_N; }
  else if (bid < 2*NB_N+NB_C){ seg=2; rb=bid-NB_N-NB_C; }
  else { seg=3; rb=bid-2*NB_N-NB_C; }
  const int* cnt = seg==0?c0 : seg==1?c1 : seg==2?c2 : c3;
  int* offs = seg==0?o0 : seg==1?o1 : seg==2?o2 : o3;
  int* bs   = seg==0?b0 : seg==1?b1 : seg==2?b2 : b3;
  int M = (seg & 1) ? NCc : Nn;
  int tid = threadIdx.x;
  int i = rb*256 + tid;
  int v = (i < M) ? cnt[i] : 0;
  s[tid] = v; __syncthreads();
  for (int d = 1; d < 256; d <<= 1){
    int t = (tid >= d) ? s[tid-d] : 0;
    __syncthreads();
    s[tid] += t;
    __syncthreads();
  }
  if (i < M) offs[i] = s[tid] - v;
  if (tid == 255) bs[rb] = s[255];
}

__global__ __launch_bounds__(512) void k_spine(int* __restrict__ b0, int* __restrict__ b1,
                      int* __restrict__ b2, int* __restrict__ b3){
  __shared__ int s[512];
  int tid = threadIdx.x, seg = tid >> 7, lane = tid & 127;
  int NB = (seg & 1) ? NB_C : NB_N;
  int* bp = seg==0?b0 : seg==1?b1 : seg==2?b2 : b3;
  int v = (lane < NB) ? bp[lane] : 0;
  s[tid] = v; __syncthreads();
  for (int d = 1; d < 128; d <<= 1){
    int t = (lane >= d) ? s[tid-d] : 0;
    __syncthreads();
    s[tid] += t;
    __syncthreads();
  }
  if (lane < NB) bp[lane] = s[tid] - v;
}

__global__ __launch_bounds__(256) void k_scan_fix(
    int* __restrict__ o0, int* __restrict__ o1, int* __restrict__ o2, int* __restrict__ o3,
    const int* __restrict__ b0, const int* __restrict__ b1,
    const int* __restrict__ b2, const int* __restrict__ b3){
  int i = blockIdx.x*256 + threadIdx.x;
  if (i < Nn) o0[i] += b0[i >> 8];
  else if ((i -= Nn) < NCc) o1[i] += b1[i >> 8];
  else if ((i -= NCc) < Nn) o2[i] += b2[i >> 8];
  else if ((i -= Nn) < NCc) o3[i] += b3[i >> 8];
}

// ---------- place: edge perms + assignment CSRs ----------
__global__ __launch_bounds__(256) void k_place(const int* __restrict__ ei, const int* __restrict__ cei,
                      const int* __restrict__ n2c,
                      const int* __restrict__ offs_n, const int* __restrict__ offs_c,
                      const int* __restrict__ offs_an, const int* __restrict__ offs_ac,
                      int* __restrict__ cur_n, int* __restrict__ cur_c,
                      int* __restrict__ cur_an, int* __restrict__ cur_ac,
                      int* __restrict__ perm_n, int* __restrict__ perm_c,
                      int* __restrict__ an2c, int* __restrict__ ac2n){
  int i = blockIdx.x*256 + threadIdx.x;
  if (i < Ee){
    int s = ei[i];
    perm_n[offs_n[s] + atomicAdd(&cur_n[s], 1)] = i;
  } else if ((i -= Ee) < ECc){
    int s = cei[i];
    perm_c[offs_c[s] + atomicAdd(&cur_c[s], 1)] = i;
  } else if ((i -= ECc) < Aa){
    int c = n2c[Aa + i];
    an2c[offs_ac[c] + atomicAdd(&cur_ac[c], 1)] = n2c[i];
  } else if ((i -= Aa) < Aa){
    int nd = n2c[i];
    ac2n[offs_an[nd] + atomicAdd(&cur_an[nd], 1)] = n2c[Aa + i];
  }
}

// ---------- gather edge payloads into sorted order ----------
__global__ __launch_bounds__(256) void k_gather(const int* __restrict__ ei, const int* __restrict__ cei,
                       const int* __restrict__ perm_n, const int* __restrict__ perm_c,
                       const void* __restrict__ ef, const void* __restrict__ cef,
                       const int* __restrict__ flag,
                       int2* __restrict__ sdp_n, float* __restrict__ efp_n,
                       int2* __restrict__ sdp_c, float* __restrict__ efp_c){
  int i = blockIdx.x*256 + threadIdx.x;
  int f = *flag;
  if (i < Ee*8){
    int p = i >> 3, j = i & 7;
    int e = perm_n[p];
    efp_n[i] = ldw(ef, (long)e*8 + j, f);
    if (j == 0) sdp_n[p] = make_int2(ei[e], ei[Ee + e]);
  } else if ((i -= Ee*8) < ECc*8){
    int p = i >> 3, j = i & 7;
    int e = perm_c[p];
    efp_c[i] = ldw(cef, (long)e*8 + j, f);
    if (j == 0) sdp_c[p] = make_int2(cei[e], cei[ECc + e]);
  }
}

// ---------- pack all 4 weight sets ----------
__global__ __launch_bounds__(256) void k_wpack_all(const void* __restrict__ nn2w, const void* __restrict__ nn2b,
                          const void* __restrict__ rootw,
                          const void* __restrict__ cnn2w, const void* __restrict__ cnn2b,
                          const void* __restrict__ crootw,
                          const int* __restrict__ flag, u16* __restrict__ Wp4){
  int i = blockIdx.x*256 + threadIdx.x;
  if (i >= 4*WPSZ) return;
  int set = i / WPSZ, j = i - set*WPSZ;
  int l = set >> 1, isC = set & 1;
  const void* W2 = isC ? cnn2w : nn2w;
  const void* B2 = isC ? cnn2b : nn2b;
  const void* RW = isC ? crootw : rootw;
  int f = *flag;
  int col = j >> 5, ii = j & 31;
  float v;
  if (col < 1024)      v = ldw(W2, (long)l*32768 + ((col>>5)<<10) + (ii<<5) + (col&31), f);
  else if (col < 1056) v = ldw(B2, (long)l*1024 + (ii<<5) + (col-1024), f);
  else                 v = ldw(RW, (long)l*1024 + (ii<<5) + (col-1056), f);
  Wp4[i] = f2b(v);
}

// ---------- fused conv: vectorized raw-base read + MFMA T + streaming edges (depth-2) ----------
__global__ __launch_bounds__(512) void k_conv_fused(const void* __restrict__ base, int braw,
                           const float* __restrict__ addagg, const int* __restrict__ adddeg, int M,
                           const int2* __restrict__ sdp, const float* __restrict__ efp,
                           const int* __restrict__ offs, int E_,
                           const void* __restrict__ w1, long w1off,
                           const void* __restrict__ b1, long b1off,
                           const u16* __restrict__ Wp,
                           const void* __restrict__ rb, long rboff,
                           const int* __restrict__ flag,
                           float* __restrict__ feat_root, float* __restrict__ agg){
  __shared__ __align__(16) u16 Ts[16*TSP];
  __shared__ float w1s[256];
  __shared__ __align__(8) u32 hws[8][4][16];
  int tid = threadIdx.x;
  int w = tid >> 6, lane = tid & 63;
  int quad = lane >> 4, lm = lane & 15;
  int n0 = blockIdx.x * 16;
  int f = *flag;
  if (tid < 256) w1s[tid] = ldw(w1, w1off + tid, f);
  float bb0 = ldw(b1, b1off + 2*lm, f);
  float bb1 = ldw(b1, b1off + 2*lm + 1, f);
  // x fragment: vectorized loads on both dtype paths
  int n = n0 + lm;
  int nc = n < M ? n : M-1;
  long bidx = (long)nc*32 + quad*8;
  float fv[8];
  if (braw && f == 0){
    uint4 q = *(const uint4*)((const u16*)base + bidx);
    fv[0]=bfl(q.x); fv[1]=bfh(q.x); fv[2]=bfl(q.y); fv[3]=bfh(q.y);
    fv[4]=bfl(q.z); fv[5]=bfh(q.z); fv[6]=bfl(q.w); fv[7]=bfh(q.w);
  } else {
    const float4* bp = (const float4*)((const float*)base + bidx);
    float4 q0 = bp[0], q1 = bp[1];
    fv[0]=q0.x; fv[1]=q0.y; fv[2]=q0.z; fv[3]=q0.w;
    fv[4]=q1.x; fv[5]=q1.y; fv[6]=q1.z; fv[7]=q1.w;
  }
  if (addagg){
    int dg = adddeg[nc];
    float d = (float)(dg > 1 ? dg : 1);
    const float4* ap = (const float4*)(addagg + (size_t)nc*32 + quad*8);
    float4 a0 = ap[0], a1 = ap[1];
    float inv = 1.f/d;
    fv[0]+=a0.x*inv; fv[1]+=a0.y*inv; fv[2]+=a0.z*inv; fv[3]+=a0.w*inv;
    fv[4]+=a1.x*inv; fv[5]+=a1.y*inv; fv[6]+=a1.z*inv; fv[7]+=a1.w*inv;
  }
  s16x8 bfrag;
  #pragma unroll
  for (int j = 0; j < 8; j++) bfrag[j] = (short)f2b(fv[j]);
  // phase 1: wave w handles col-tiles [9w, 9w+9) of 68
  #pragma unroll 1
  for (int ti = 0; ti < 9; ti++){
    int ct = w*9 + ti;
    if (ct >= 68) break;
    int colbase = ct*16;
    s16x8 afrag = *(const s16x8*)(Wp + (size_t)(colbase + lm)*32 + quad*8);
    f32x4 acc = {0.f, 0.f, 0.f, 0.f};
    acc = __builtin_amdgcn_mfma_f32_16x16x32_bf16(afrag, bfrag, acc, 0, 0, 0);
    int cb = colbase + quad*4;
    if (ct < 66){
      u32 lo = (u32)f2b(acc[0]) | ((u32)f2b(acc[1]) << 16);
      u32 hi = (u32)f2b(acc[2]) | ((u32)f2b(acc[3]) << 16);
      *(uint2*)&Ts[lm*TSP + cb] = make_uint2(lo, hi);
    } else if (n < M){
      int o = cb - 1056;
      float4 v = make_float4(acc[0] + ldw(rb, rboff+o,   f),
                             acc[1] + ldw(rb, rboff+o+1, f),
                             acc[2] + ldw(rb, rboff+o+2, f),
                             acc[3] + ldw(rb, rboff+o+3, f));
      *(float4*)&feat_root[(size_t)n*32 + o] = v;
    }
  }
  __syncthreads();
  // phase 2: streaming edges, 4/wave-iter, depth-2 prefetch
  int lo = offs[n0];
  int hi = (n0 + 16 < M) ? offs[n0 + 16] : E_;
  int eg = quad, kk = lm;
  int pos = lo + w*4;
  float ef0 = 0.f, ef1 = 0.f; int sd0 = 0, sd1 = 0;
  if (lane < 32){
    int idx = pos*8 + lane;        if (idx < hi*8) ef0 = efp[idx];
    idx = (pos+32)*8 + lane;       if (idx < hi*8) ef1 = efp[idx];
  } else if (lane < 40){
    int idx = pos*2 + (lane-32);   if (idx < hi*2) sd0 = ((const int*)sdp)[idx];
    idx = (pos+32)*2 + (lane-32);  if (idx < hi*2) sd1 = ((const int*)sdp)[idx];
  }
  for (; pos < hi; pos += 32){
    int np = pos + 64;
    float ef2 = 0.f; int sd2 = 0;
    if (lane < 32){ int idx = np*8 + lane; if (idx < hi*8) ef2 = efp[idx]; }
    else if (lane < 40){ int idx = np*2 + (lane-32); if (idx < hi*2) sd2 = ((const int*)sdp)[idx]; }
    int sn = __shfl(sd0, 32 + 2*eg);
    int dn = __shfl(sd0, 33 + 2*eg);
    bool valid = (pos + eg < hi);
    int sr = sn - n0; sr = sr < 0 ? 0 : (sr > 15 ? 15 : sr);
    float a0 = bb0, a1 = bb1;
    #pragma unroll
    for (int j = 0; j < 8; j++){
      float ev = __shfl(ef0, eg*8 + j);
      a0 += ev * w1s[j*32 + 2*kk];
      a1 += ev * w1s[j*32 + 2*kk+1];
    }
    hws[w][eg][kk] = pk2(fmaxf(a0, 0.f), fmaxf(a1, 0.f));
    if (valid){
      const u16* Tr = &Ts[sr*TSP];
      u32 vb = *(const u32*)&Tr[1024 + 2*kk];   // b2 row (h=1)
      float m0 = bfl(vb), m1 = bfh(vb);
      #pragma unroll
      for (int kq = 0; kq < 16; kq++){
        u32 hp = hws[w][eg][kq];
        float h0 = bfl(hp), h1 = bfh(hp);
        u32 v0 = *(const u32*)&Tr[(2*kq)*32 + 2*kk];
        u32 v1 = *(const u32*)&Tr[(2*kq+1)*32 + 2*kk];
        m0 += h0*bfl(v0) + h1*bfl(v1);
        m1 += h0*bfh(v0) + h1*bfh(v1);
      }
      float* ap = agg + (size_t)dn*32 + 2*kk;
      atomicAdd(ap,   m0);
      atomicAdd(ap+1, m1);
    }
    ef0 = ef1; sd0 = sd1; ef1 = ef2; sd1 = sd2;
  }
}

// ---------- fused: feat = relu(agg/deg + froot); m = feat@w+b; scatter m into sagg ----------
__global__ __launch_bounds__(256) void k_update_lin(const float* __restrict__ agg, const int* __restrict__ deg,
                           const float* __restrict__ feat_root, int M,
                           const void* __restrict__ w, long woff,
                           const void* __restrict__ b, long boff,
                           const int* __restrict__ flag,
                           float* __restrict__ feat,
                           const int* __restrict__ sidx, const int* __restrict__ soffs,
                           const int* __restrict__ sdeg, float* __restrict__ sagg){
  __shared__ float wsm[1024], bs[32], rows[8][33];
  int tid = threadIdx.x;
  int f = *flag;
  for (int idx = tid; idx < 1024; idx += 256) wsm[idx] = ldw(w, woff + idx, f);
  if (tid < 32) bs[tid] = ldw(b, boff + tid, f);
  int nl = tid >> 5, o = tid & 31;
  int n = blockIdx.x*8 + nl;
  long i = (long)n*32 + o;
  if (n < M){
    int dg = deg[n];
    float d = (float)(dg > 1 ? dg : 1);
    float v = fmaxf(agg[i]/d + feat_root[i], 0.f);
    rows[nl][o] = v;
    feat[i] = v;
  }
  __syncthreads();
  if (n >= M) return;
  float acc = bs[o];
  #pragma unroll
  for (int j = 0; j < 32; j++) acc += rows[nl][j]*wsm[j*32+o];
  int slo = soffs[n], scnt = sdeg[n];
  for (int a = 0; a < scnt; a++)
    atomicAdd(&sagg[(size_t)sidx[slo + a]*32 + o], acc);
}

// ---------- final store ----------
__global__ __launch_bounds__(256) void k_store(const float* __restrict__ x, const float* __restrict__ xagg,
                      const int* __restrict__ xdeg, const float* __restrict__ c,
                      void* __restrict__ out, const int* __restrict__ flag){
  int i = blockIdx.x*256 + threadIdx.x;
  int tot = Nn*32 + NCc*32;
  if (i >= tot) return;
  float v;
  if (i < Nn*32){
    int n = i >> 5;
    int dg = xdeg[n];
    float d = (float)(dg > 1 ? dg : 1);
    v = x[i] + xagg[i]/d;
  } else v = c[i - Nn*32];
  if (*flag) ((float*)out)[i] = v;
  else       ((u16*)out)[i]   = f2b(v);
}

extern "C" void kernel_launch(void* const* d_in, const int* in_sizes, int n_in,
                              void* d_out, int out_size, void* d_ws, size_t ws_size,
                              hipStream_t stream){
  const int* ei  = (const int*)d_in[1];
  const int* n2c = (const int*)d_in[4];
  const int* cei = (const int*)d_in[5];
  const void *efr = d_in[2], *cefr = d_in[6];
  const void *nn1w = d_in[7], *nn1b = d_in[8], *nn2w = d_in[9], *nn2b = d_in[10],
             *rootw = d_in[11], *rootb = d_in[12], *n2cw = d_in[13], *n2cb = d_in[14],
             *cnn1w = d_in[15], *cnn1b = d_in[16], *cnn2w = d_in[17], *cnn2b = d_in[18],
             *crootw = d_in[19], *crootb = d_in[20], *c2nw = d_in[21], *c2nb = d_in[22];

  char* ws = (char*)d_ws;
  size_t off = 0;
  auto alloc = [&](size_t bytes){ void* p = ws + off; off += (bytes + 255) & ~(size_t)255; return p; };

  // ---- zeroed region (single memset) ----
  size_t zstart = off;
  float* aggE0  = (float*)alloc((size_t)Nn*32*4);
  float* aggE1  = (float*)alloc((size_t)Nn*32*4);
  float* caggE0 = (float*)alloc((size_t)NCc*32*4);
  float* caggE1 = (float*)alloc((size_t)NCc*32*4);
  float* caggS0 = (float*)alloc((size_t)NCc*32*4);
  float* caggS1 = (float*)alloc((size_t)NCc*32*4);
  float* aggS0  = (float*)alloc((size_t)Nn*32*4);
  float* aggS1  = (float*)alloc((size_t)Nn*32*4);
  int* deg_nd  = (int*)alloc((size_t)Nn*4);
  int* deg_ce  = (int*)alloc((size_t)NCc*4);
  int* deg_n2c = (int*)alloc((size_t)NCc*4);
  int* deg_c2n = (int*)alloc((size_t)Nn*4);
  int* cnt_sn  = (int*)alloc((size_t)Nn*4);
  int* cnt_sc  = (int*)alloc((size_t)NCc*4);
  int* cur_n   = (int*)alloc((size_t)Nn*4);
  int* cur_c   = (int*)alloc((size_t)NCc*4);
  int* cur_an  = (int*)alloc((size_t)Nn*4);
  int* cur_ac  = (int*)alloc((size_t)NCc*4);
  u32* maxbits = (u32*)alloc(256);
  int* zcnt = (int*)((char*)maxbits + 4);
  int* flag = (int*)((char*)maxbits + 8);
  int* done = (int*)((char*)maxbits + 12);
  size_t zbytes = off - zstart;

  // ---- non-zeroed ----
  float* xB  = (float*)alloc((size_t)Nn*32*4);
  float* xC  = (float*)alloc((size_t)Nn*32*4);
  float* cC0 = (float*)alloc((size_t)NCc*32*4);
  float* cC1 = (float*)alloc((size_t)NCc*32*4);
  float* frn = (float*)alloc((size_t)Nn*32*4);
  float* frc = (float*)alloc((size_t)NCc*32*4);
  int* offs_n  = (int*)alloc((size_t)Nn*4);
  int* offs_c  = (int*)alloc((size_t)NCc*4);
  int* offs_an = (int*)alloc((size_t)Nn*4);
  int* offs_ac = (int*)alloc((size_t)NCc*4);
  int* bs0 = (int*)alloc(512); int* bs1 = (int*)alloc(512);
  int* bs2 = (int*)alloc(512); int* bs3 = (int*)alloc(512);
  int* perm_n = (int*)alloc((size_t)Ee*4);
  int* perm_c = (int*)alloc((size_t)ECc*4);
  int* an2c = (int*)alloc((size_t)Aa*4);
  int* ac2n = (int*)alloc((size_t)Aa*4);
  int2* sdp_n = (int2*)alloc((size_t)Ee*8);
  int2* sdp_c = (int2*)alloc((size_t)ECc*8);
  float* efp_n = (float*)alloc((size_t)Ee*8*4);
  float* efp_c = (float*)alloc((size_t)ECc*8*4);
  u16* Wp4 = (u16*)alloc((size_t)4*WPSZ*2);

  auto nb = [](int n){ return (n + 255)/256; };

  // 1. memset accumulators/counters
  hipMemsetAsync(ws + zstart, 0, zbytes, stream);
  // 2. dtype detect
  k_detect<<<256,256,0,stream>>>((const u16*)d_in[0], Nn*32, maxbits, zcnt, done, flag);
  // 3. histograms + 4-way scan + counting sorts + payload gather
  k_count_all<<<nb(2*Ee + 2*ECc + 2*Aa),256,0,stream>>>(ei, cei, n2c,
      deg_nd, deg_ce, deg_n2c, deg_c2n, cnt_sn, cnt_sc);
  k_scan_block<<<2*(NB_N+NB_C),256,0,stream>>>(cnt_sn, cnt_sc, deg_c2n, deg_n2c,
      offs_n, offs_c, offs_an, offs_ac, bs0, bs1, bs2, bs3);
  k_spine<<<1,512,0,stream>>>(bs0, bs1, bs2, bs3);
  k_scan_fix<<<nb(2*(Nn+NCc)),256,0,stream>>>(offs_n, offs_c, offs_an, offs_ac,
      bs0, bs1, bs2, bs3);
  k_place<<<nb(Ee+ECc+2*Aa),256,0,stream>>>(ei, cei, n2c, offs_n, offs_c, offs_an, offs_ac,
      cur_n, cur_c, cur_an, cur_ac, perm_n, perm_c, an2c, ac2n);
  k_gather<<<nb(8*(Ee+ECc)),256,0,stream>>>(ei, cei, perm_n, perm_c, efr, cefr, flag,
      sdp_n, efp_n, sdp_c, efp_c);
  // 4. pack weights
  k_wpack_all<<<nb(4*WPSZ),256,0,stream>>>(nn2w, nn2b, rootw, cnn2w, cnn2b, crootw, flag, Wp4);

  int Gn = (Nn + 15)/16, Gc = (NCc + 15)/16;

  // ---- layer 0 ----
  k_conv_fused<<<Gn,512,0,stream>>>(d_in[0], 1, nullptr, nullptr, Nn, sdp_n, efp_n, offs_n, Ee,
      nn1w, 0, nn1b, 0, Wp4 + 0*WPSZ, rootb, 0, flag, frn, aggE0);
  k_update_lin<<<(Nn+7)/8,256,0,stream>>>(aggE0, deg_nd, frn, Nn, n2cw, 0, n2cb, 0, flag,
      xB, ac2n, offs_an, deg_c2n, caggS0);
  k_conv_fused<<<Gc,512,0,stream>>>(d_in[3], 1, caggS0, deg_n2c, NCc, sdp_c, efp_c, offs_c, ECc,
      cnn1w, 0, cnn1b, 0, Wp4 + 1*WPSZ, crootb, 0, flag, frc, caggE0);
  k_update_lin<<<(NCc+7)/8,256,0,stream>>>(caggE0, deg_ce, frc, NCc, c2nw, 0, c2nb, 0, flag,
      cC0, an2c, offs_ac, deg_n2c, aggS0);
  // ---- layer 1 ----
  k_conv_fused<<<Gn,512,0,stream>>>(xB, 0, aggS0, deg_c2n, Nn, sdp_n, efp_n, offs_n, Ee,
      nn1w, 256, nn1b, 32, Wp4 + 2*WPSZ, rootb, 32, flag, frn, aggE1);
  k_update_lin<<<(Nn+7)/8,256,0,stream>>>(aggE1, deg_nd, frn, Nn, n2cw, 1024, n2cb, 32, flag,
      xC, ac2n, offs_an, deg_c2n, caggS1);
  k_conv_fused<<<Gc,512,0,stream>>>(cC0, 0, caggS1, deg_n2c, NCc, sdp_c, efp_c, offs_c, ECc,
      cnn1w, 256, cnn1b, 32, Wp4 + 3*WPSZ, crootb, 32, flag, frc, caggE1);
  k_update_lin<<<(NCc+7)/8,256,0,stream>>>(caggE1, deg_ce, frc, NCc, c2nw, 1024, c2nb, 32, flag,
      cC1, an2c, offs_ac, deg_n2c, aggS1);
  // ---- output ----
  k_store<<<nb(Nn*32 + NCc*32),256,0,stream>>>(xC, aggS1, deg_c2n, cC1, d_out, flag);
}